// Round 1
// baseline (358.394 us; speedup 1.0000x reference)
//
#include <hip/hip_runtime.h>
#include <hip/hip_bf16.h>

#define BB 16
#define TT 2048
#define DD 128

typedef __bf16 bf16x8 __attribute__((ext_vector_type(8)));
typedef __bf16 bf16x4 __attribute__((ext_vector_type(4)));
typedef float f32x4 __attribute__((ext_vector_type(4)));

__device__ __forceinline__ float warp16_max(float v) {
    v = fmaxf(v, __shfl_xor(v, 1));
    v = fmaxf(v, __shfl_xor(v, 2));
    v = fmaxf(v, __shfl_xor(v, 4));
    v = fmaxf(v, __shfl_xor(v, 8));
    return v;
}
__device__ __forceinline__ float warp16_sum(float v) {
    v += __shfl_xor(v, 1);
    v += __shfl_xor(v, 2);
    v += __shfl_xor(v, 4);
    v += __shfl_xor(v, 8);
    return v;
}

// One block = 4 waves, 64 q-rows (16 per wave). KV tiles of 64 keys.
// K in LDS row-major bf16 with XOR swizzle ((key&7)<<4) on the byte offset.
// V in LDS transposed [d=128][key, stride 72] bf16 (pad keeps b128 reads clean).
// P per-wave [16][stride 72] bf16 for the PV A-operand.
__global__ __launch_bounds__(256) void attn_fwd(
    const float* __restrict__ Q, const float* __restrict__ K,
    const float* __restrict__ V, float* __restrict__ O)
{
    __shared__ __align__(16) unsigned short Klds[64 * 128];
    __shared__ __align__(16) unsigned short Vt[128 * 72];
    __shared__ __align__(16) unsigned short Plds[4][16 * 72];

    const int tid  = threadIdx.x;
    const int lane = tid & 63;
    const int w    = tid >> 6;       // wave 0..3
    const int x    = lane & 15;
    const int hi   = lane >> 4;

    const int qb = 31 - blockIdx.x;  // reversed: heavy blocks dispatch first
    const int b  = blockIdx.y;
    const int qrow0 = qb * 64 + w * 16;

    const float* qp    = Q + ((size_t)b * TT + qrow0) * DD;
    const float* kbase = K + (size_t)b * TT * DD;
    const float* vbase = V + (size_t)b * TT * DD;

    const float SCALE = 0.08838834764831845f; // 1/sqrt(128)

    // ---- preload Q fragments: A[m=x][k = kc*32 + 8*hi + i] ----
    bf16x8 qf[4];
    #pragma unroll
    for (int kc = 0; kc < 4; ++kc) {
        const float4* s0 = (const float4*)(qp + x * DD + kc * 32 + 8 * hi);
        float4 f0 = s0[0], f1 = s0[1];
        bf16x8 t;
        t[0] = (__bf16)f0.x; t[1] = (__bf16)f0.y; t[2] = (__bf16)f0.z; t[3] = (__bf16)f0.w;
        t[4] = (__bf16)f1.x; t[5] = (__bf16)f1.y; t[6] = (__bf16)f1.z; t[7] = (__bf16)f1.w;
        qf[kc] = t;
    }

    f32x4 o[8];
    #pragma unroll
    for (int nt = 0; nt < 8; ++nt) o[nt] = (f32x4){0.f, 0.f, 0.f, 0.f};
    float mr[4] = {-1e30f, -1e30f, -1e30f, -1e30f};
    float lr[4] = {0.f, 0.f, 0.f, 0.f};

    const int ntile = qb + 1;
    for (int t = 0; t < ntile; ++t) {
        const int kb = t * 64;
        __syncthreads();  // prev tile's PV reads done before restaging

        // ---- stage K tile (64 keys x 128 d), swizzled ----
        {
            const float* kp = kbase + (size_t)kb * DD;
            const int krow = tid >> 5;          // 0..7
            const int d4   = (tid & 31) * 4;
            #pragma unroll
            for (int it = 0; it < 8; ++it) {
                int key = it * 8 + krow;
                float4 f = *(const float4*)(kp + (size_t)key * DD + d4);
                bf16x4 h;
                h[0] = (__bf16)f.x; h[1] = (__bf16)f.y;
                h[2] = (__bf16)f.z; h[3] = (__bf16)f.w;
                int off = key * 256 + ((d4 * 2) ^ ((key & 7) << 4));
                *(bf16x4*)((char*)Klds + off) = h;
            }
        }
        // ---- stage V^T tile: Vt[d][key], stride 72 ----
        {
            const float* vp = vbase + (size_t)kb * DD;
            const int dd = tid & 127;
            const int g  = tid >> 7;
            #pragma unroll
            for (int m4 = 0; m4 < 4; ++m4) {
                int key8 = (g * 4 + m4) * 8;
                bf16x8 h;
                #pragma unroll
                for (int j = 0; j < 8; ++j)
                    h[j] = (__bf16)vp[(size_t)(key8 + j) * DD + dd];
                *(bf16x8*)(&Vt[dd * 72 + key8]) = h;
            }
        }
        __syncthreads();

        // ---- QK^T : S[q=4*hi+r][key = nt*16 + x] ----
        const bool diag  = (t == qb);
        const int  ntmax = diag ? w : 3;
        float s[4][4];
        #pragma unroll
        for (int nt = 0; nt < 4; ++nt) {
            if (nt <= ntmax) {
                f32x4 acc = (f32x4){0.f, 0.f, 0.f, 0.f};
                int key = nt * 16 + x;
                #pragma unroll
                for (int kc = 0; kc < 4; ++kc) {
                    int off = key * 256 + ((kc * 64 + 16 * hi) ^ ((key & 7) << 4));
                    bf16x8 bfr = *(const bf16x8*)((const char*)Klds + off);
                    acc = __builtin_amdgcn_mfma_f32_16x16x32_bf16(qf[kc], bfr, acc, 0, 0, 0);
                }
                #pragma unroll
                for (int r = 0; r < 4; ++r) {
                    float val = acc[r] * SCALE;
                    if (diag && (kb + key > qrow0 + 4 * hi + r)) val = -1e30f;
                    s[nt][r] = val;
                }
            } else {
                #pragma unroll
                for (int r = 0; r < 4; ++r) s[nt][r] = -1e30f;
            }
        }

        // ---- online softmax (wave-parallel, per row r) ----
        #pragma unroll
        for (int r = 0; r < 4; ++r) {
            float mx = fmaxf(fmaxf(s[0][r], s[1][r]), fmaxf(s[2][r], s[3][r]));
            mx = warp16_max(mx);
            float mnew  = fmaxf(mr[r], mx);
            float alpha = __expf(mr[r] - mnew);
            mr[r] = mnew;
            float sum = 0.f;
            #pragma unroll
            for (int nt = 0; nt < 4; ++nt) {
                float p = __expf(s[nt][r] - mnew);
                s[nt][r] = p;
                sum += p;
            }
            sum = warp16_sum(sum);
            lr[r] = lr[r] * alpha + sum;
            #pragma unroll
            for (int nt = 0; nt < 8; ++nt) o[nt][r] *= alpha;
        }

        // ---- write P to per-wave LDS [q_local][key], stride 72 ----
        #pragma unroll
        for (int nt = 0; nt < 4; ++nt) {
            #pragma unroll
            for (int r = 0; r < 4; ++r) {
                Plds[w][(4 * hi + r) * 72 + nt * 16 + x] =
                    __builtin_bit_cast(unsigned short, (__bf16)s[nt][r]);
            }
        }
        __syncthreads();

        // ---- PV : O[q][d = nt*16 + x] += P(16x64) * V(64x128) ----
        #pragma unroll
        for (int kc = 0; kc < 2; ++kc) {
            bf16x8 af = *(const bf16x8*)(&Plds[w][x * 72 + kc * 32 + 8 * hi]);
            #pragma unroll
            for (int nt = 0; nt < 8; ++nt) {
                bf16x8 bfr = *(const bf16x8*)(&Vt[(nt * 16 + x) * 72 + kc * 32 + 8 * hi]);
                o[nt] = __builtin_amdgcn_mfma_f32_16x16x32_bf16(af, bfr, o[nt], 0, 0, 0);
            }
        }
    }

    // ---- epilogue: normalize and store fp32 ----
    float* op = O + ((size_t)b * TT + qrow0) * DD;
    #pragma unroll
    for (int r = 0; r < 4; ++r) {
        float inv = 1.0f / lr[r];
        #pragma unroll
        for (int nt = 0; nt < 8; ++nt)
            op[(size_t)(4 * hi + r) * DD + nt * 16 + x] = o[nt][r] * inv;
    }
}

extern "C" void kernel_launch(void* const* d_in, const int* in_sizes, int n_in,
                              void* d_out, int out_size, void* d_ws, size_t ws_size,
                              hipStream_t stream) {
    const float* q = (const float*)d_in[0];
    const float* k = (const float*)d_in[1];
    const float* v = (const float*)d_in[2];
    // d_in[3] is the causal mask; causality is applied analytically.
    float* out = (float*)d_out;
    attn_fwd<<<dim3(32, 16), 256, 0, stream>>>(q, k, v, out);
}

// Round 2
// 177.048 us; speedup vs baseline: 2.0243x; 2.0243x over previous
//
#include <hip/hip_runtime.h>
#include <hip/hip_bf16.h>

#define TT 2048
#define DD 128

typedef __bf16 bf16x8 __attribute__((ext_vector_type(8)));
typedef __bf16 bf16x4 __attribute__((ext_vector_type(4)));
typedef float f32x4 __attribute__((ext_vector_type(4)));

__device__ __forceinline__ float warp16_max(float v) {
    v = fmaxf(v, __shfl_xor(v, 1));
    v = fmaxf(v, __shfl_xor(v, 2));
    v = fmaxf(v, __shfl_xor(v, 4));
    v = fmaxf(v, __shfl_xor(v, 8));
    return v;
}
__device__ __forceinline__ float warp16_sum(float v) {
    v += __shfl_xor(v, 1);
    v += __shfl_xor(v, 2);
    v += __shfl_xor(v, 4);
    v += __shfl_xor(v, 8);
    return v;
}

// One block = 4 waves, 64 q-rows (16/wave). KV tiles of 64 keys, double-buffered.
// Split-K: block (qb, b, c) processes KV tiles [c*CHUNK, min(qb+1, (c+1)*CHUNK)).
// Full-range blocks write O directly; partial blocks write unnormalized O + m,l
// to workspace; attn_combine merges.
__global__ __launch_bounds__(256) void attn_partial(
    const float* __restrict__ Q, const float* __restrict__ K,
    const float* __restrict__ V, float* __restrict__ O,
    float* __restrict__ WS, int CHUNK)
{
    __shared__ __align__(16) unsigned short Klds[2][64 * 128];
    __shared__ __align__(16) unsigned short Vt[2][128 * 72];
    __shared__ __align__(16) unsigned short Plds[4][16 * 72];

    const int qb = blockIdx.x;
    const int b  = blockIdx.y;
    const int ntile = qb + 1;
    const int t0 = blockIdx.z * CHUNK;
    if (t0 >= ntile) return;                    // inactive chunk
    const int t1 = min(ntile, t0 + CHUNK);

    const int tid  = threadIdx.x;
    const int lane = tid & 63;
    const int w    = tid >> 6;       // wave 0..3
    const int x    = lane & 15;
    const int hi   = lane >> 4;
    const int qrow0 = qb * 64 + w * 16;

    const float* qp    = Q + ((size_t)b * TT + qrow0) * DD;
    const float* kbase = K + (size_t)b * TT * DD;
    const float* vbase = V + (size_t)b * TT * DD;

    const float SCALE = 0.08838834764831845f; // 1/sqrt(128)

    // staging thread mapping
    const int krow = tid >> 5;        // 0..7
    const int d4   = (tid & 31) * 4;  // 0..124
    const int dd   = tid & 127;       // 0..127
    const int g    = tid >> 7;        // 0..1

    // ---- preload Q fragments: A[m=x][k = kc*32 + 8*hi + i] ----
    bf16x8 qf[4];
    #pragma unroll
    for (int kc = 0; kc < 4; ++kc) {
        const float4* s0 = (const float4*)(qp + x * DD + kc * 32 + 8 * hi);
        float4 f0 = s0[0], f1 = s0[1];
        bf16x8 t;
        t[0] = (__bf16)f0.x; t[1] = (__bf16)f0.y; t[2] = (__bf16)f0.z; t[3] = (__bf16)f0.w;
        t[4] = (__bf16)f1.x; t[5] = (__bf16)f1.y; t[6] = (__bf16)f1.z; t[7] = (__bf16)f1.w;
        qf[kc] = t;
    }

    f32x4 o[8];
    #pragma unroll
    for (int nt = 0; nt < 8; ++nt) o[nt] = (f32x4){0.f, 0.f, 0.f, 0.f};
    float mr[4] = {-1e30f, -1e30f, -1e30f, -1e30f};
    float lr[4] = {0.f, 0.f, 0.f, 0.f};

    float4 kreg[8];
    float  vreg[32];

    auto LOAD = [&](int t) {
        const float* kp = kbase + (size_t)(t * 64) * DD;
        const float* vp = vbase + (size_t)(t * 64) * DD;
        #pragma unroll
        for (int it = 0; it < 8; ++it)
            kreg[it] = *(const float4*)(kp + (size_t)(it * 8 + krow) * DD + d4);
        #pragma unroll
        for (int m4 = 0; m4 < 4; ++m4)
            #pragma unroll
            for (int j = 0; j < 8; ++j)
                vreg[m4 * 8 + j] = vp[(size_t)((g * 4 + m4) * 8 + j) * DD + dd];
    };
    auto WRITE = [&](int buf) {
        char* kb8 = (char*)Klds[buf];
        #pragma unroll
        for (int it = 0; it < 8; ++it) {
            int key = it * 8 + krow;
            float4 f = kreg[it];
            bf16x4 h;
            h[0] = (__bf16)f.x; h[1] = (__bf16)f.y;
            h[2] = (__bf16)f.z; h[3] = (__bf16)f.w;
            *(bf16x4*)(kb8 + key * 256 + ((d4 * 2) ^ ((key & 7) << 4))) = h;
        }
        #pragma unroll
        for (int m4 = 0; m4 < 4; ++m4) {
            bf16x8 h;
            #pragma unroll
            for (int j = 0; j < 8; ++j) h[j] = (__bf16)vreg[m4 * 8 + j];
            *(bf16x8*)(&Vt[buf][dd * 72 + (g * 4 + m4) * 8]) = h;
        }
    };

    // prolog: stage first tile
    LOAD(t0);
    WRITE(0);
    int cur = 0;

    for (int t = t0; t < t1; ++t) {
        const int kb = t * 64;
        __syncthreads();                 // buf[cur] visible to all waves

        if (t + 1 < t1) LOAD(t + 1);     // issue next tile's loads early

        // ---- QK^T : S[q=4*hi+r][key = nt*16 + x] ----
        const bool diag  = (t == qb);
        const int  ntmax = diag ? w : 3;
        const char* kb8  = (const char*)Klds[cur];
        float s[4][4];
        #pragma unroll
        for (int nt = 0; nt < 4; ++nt) {
            if (nt <= ntmax) {
                f32x4 acc = (f32x4){0.f, 0.f, 0.f, 0.f};
                int key = nt * 16 + x;
                #pragma unroll
                for (int kc = 0; kc < 4; ++kc) {
                    int off = key * 256 + ((kc * 64 + 16 * hi) ^ ((key & 7) << 4));
                    bf16x8 bfr = *(const bf16x8*)(kb8 + off);
                    acc = __builtin_amdgcn_mfma_f32_16x16x32_bf16(qf[kc], bfr, acc, 0, 0, 0);
                }
                #pragma unroll
                for (int r = 0; r < 4; ++r) {
                    float val = acc[r] * SCALE;
                    if (diag && (kb + key > qrow0 + 4 * hi + r)) val = -1e30f;
                    s[nt][r] = val;
                }
            } else {
                #pragma unroll
                for (int r = 0; r < 4; ++r) s[nt][r] = -1e30f;
            }
        }

        // ---- online softmax (wave-parallel) ----
        #pragma unroll
        for (int r = 0; r < 4; ++r) {
            float mx = fmaxf(fmaxf(s[0][r], s[1][r]), fmaxf(s[2][r], s[3][r]));
            mx = warp16_max(mx);
            float mnew  = fmaxf(mr[r], mx);
            float alpha = __expf(mr[r] - mnew);
            mr[r] = mnew;
            float sum = 0.f;
            #pragma unroll
            for (int nt = 0; nt < 4; ++nt) {
                float p = __expf(s[nt][r] - mnew);
                s[nt][r] = p;
                sum += p;
            }
            sum = warp16_sum(sum);
            lr[r] = lr[r] * alpha + sum;
            #pragma unroll
            for (int nt = 0; nt < 8; ++nt) o[nt][r] *= alpha;
        }

        // ---- P to per-wave LDS (no barrier needed: same-wave producer/consumer) ----
        #pragma unroll
        for (int nt = 0; nt < 4; ++nt) {
            #pragma unroll
            for (int r = 0; r < 4; ++r) {
                Plds[w][(4 * hi + r) * 72 + nt * 16 + x] =
                    __builtin_bit_cast(unsigned short, (__bf16)s[nt][r]);
            }
        }

        // ---- PV : O[q][d = nt*16 + x] += P(16x64) * V(64x128) ----
        #pragma unroll
        for (int kc = 0; kc < 2; ++kc) {
            bf16x8 af = *(const bf16x8*)(&Plds[w][x * 72 + kc * 32 + 8 * hi]);
            #pragma unroll
            for (int nt = 0; nt < 8; ++nt) {
                bf16x8 bfr = *(const bf16x8*)(&Vt[cur][(nt * 16 + x) * 72 + kc * 32 + 8 * hi]);
                o[nt] = __builtin_amdgcn_mfma_f32_16x16x32_bf16(af, bfr, o[nt], 0, 0, 0);
            }
        }

        if (t + 1 < t1) WRITE(cur ^ 1);  // stage next tile into the other buffer
        cur ^= 1;
    }

    if (t0 == 0 && t1 == ntile) {
        // ---- direct epilogue: normalize and store fp32 ----
        float* op = O + ((size_t)b * TT + qrow0) * DD;
        #pragma unroll
        for (int r = 0; r < 4; ++r) {
            float inv = 1.0f / lr[r];
            #pragma unroll
            for (int nt = 0; nt < 8; ++nt)
                op[(size_t)(4 * hi + r) * DD + nt * 16 + x] = o[nt][r] * inv;
        }
    } else {
        // ---- partial epilogue: unnormalized O + m,l to workspace ----
        // slot layout: [64][128] O, [64] m, [64] l  (8320 floats)
        float* slot = WS + (size_t)((b * 16 + (qb - 16)) * 2 + blockIdx.z) * 8320;
        #pragma unroll
        for (int r = 0; r < 4; ++r) {
            int row = w * 16 + 4 * hi + r;
            #pragma unroll
            for (int nt = 0; nt < 8; ++nt)
                slot[row * 128 + nt * 16 + x] = o[nt][r];
            if (x == 0) {
                slot[8192 + row] = mr[r];
                slot[8256 + row] = lr[r];
            }
        }
    }
}

__global__ __launch_bounds__(256) void attn_combine(
    const float* __restrict__ WS, float* __restrict__ O)
{
    const int qb = 16 + blockIdx.x;
    const int b  = blockIdx.y;
    const int row = threadIdx.x >> 2;          // 0..63
    const int cg  = (threadIdx.x & 3) * 32;    // col group

    const float* s0 = WS + (size_t)((b * 16 + (qb - 16)) * 2 + 0) * 8320;
    const float* s1 = s0 + 8320;

    float m0 = s0[8192 + row], l0 = s0[8256 + row];
    float m1 = s1[8192 + row], l1 = s1[8256 + row];
    float M  = fmaxf(m0, m1);
    float e0 = __expf(m0 - M), e1 = __expf(m1 - M);
    float inv = 1.0f / (l0 * e0 + l1 * e1);

    const float* p0 = s0 + row * 128 + cg;
    const float* p1 = s1 + row * 128 + cg;
    float* op = O + ((size_t)b * TT + qb * 64 + row) * DD + cg;
    #pragma unroll
    for (int j = 0; j < 32; j += 4) {
        float4 a  = *(const float4*)(p0 + j);
        float4 bb = *(const float4*)(p1 + j);
        float4 r;
        r.x = (a.x * e0 + bb.x * e1) * inv;
        r.y = (a.y * e0 + bb.y * e1) * inv;
        r.z = (a.z * e0 + bb.z * e1) * inv;
        r.w = (a.w * e0 + bb.w * e1) * inv;
        *(float4*)(op + j) = r;
    }
}

extern "C" void kernel_launch(void* const* d_in, const int* in_sizes, int n_in,
                              void* d_out, int out_size, void* d_ws, size_t ws_size,
                              hipStream_t stream) {
    const float* q = (const float*)d_in[0];
    const float* k = (const float*)d_in[1];
    const float* v = (const float*)d_in[2];
    // d_in[3] is the causal mask; causality is applied analytically.
    float* out = (float*)d_out;

    const size_t need = (size_t)16 * 16 * 2 * 8320 * sizeof(float); // 17.04 MB
    if (ws_size >= need) {
        attn_partial<<<dim3(32, 16, 2), 256, 0, stream>>>(q, k, v, out, (float*)d_ws, 16);
        attn_combine<<<dim3(16, 16), 256, 0, stream>>>((const float*)d_ws, out);
    } else {
        attn_partial<<<dim3(32, 16, 1), 256, 0, stream>>>(q, k, v, out, (float*)d_ws, 32);
    }
}